// Round 7
// baseline (80.980 us; speedup 1.0000x reference)
//
#include <hip/hip_runtime.h>
#include <math.h>

#define NB 2
#define QN 8192
#define DIM 256
#define S_TOT 5440   // 4096+1024+256+64

typedef unsigned int uint32;
typedef _Float16 f16;
typedef __attribute__((ext_vector_type(8))) _Float16 h8;   // MFMA A/B frag (4 VGPR)
typedef __attribute__((ext_vector_type(2))) _Float16 h2;
typedef __attribute__((ext_vector_type(4))) float f32x4;   // MFMA C/D frag
typedef __attribute__((ext_vector_type(4))) uint32 u32x4;  // 16B staging

// ---------------------------------------------------------------------------
// Fused prep: ALL transposes/conversions in ONE launch.
// grid.x: [0,340) feat tiles (170 per batch), [340,368) weight tiles.
// src f32 [C=256][S] -> dst f16 [S][256].
// ---------------------------------------------------------------------------
__global__ __launch_bounds__(256) void prep_kernel(
    const float* __restrict__ f0, const float* __restrict__ f1,
    const float* __restrict__ f2, const float* __restrict__ f3,
    const float* __restrict__ W_off, const float* __restrict__ W_attn,
    const float* __restrict__ W_val, const float* __restrict__ W_out,
    f16* __restrict__ featT, f16* __restrict__ Wcat_t,
    f16* __restrict__ Wval_t, f16* __restrict__ Wout_t) {
  const int t = blockIdx.x;
  const float* src;
  f16* dst;
  int S, tb;
  if (t < 340) {
    const int b = (t >= 170) ? 1 : 0;
    const int tt = t - 170 * b;
    int soff;
    if (tt < 128)      { src = f0; S = 4096; soff = 0;    tb = tt; }
    else if (tt < 160) { src = f1; S = 1024; soff = 4096; tb = tt - 128; }
    else if (tt < 168) { src = f2; S = 256;  soff = 5120; tb = tt - 160; }
    else               { src = f3; S = 64;   soff = 5376; tb = tt - 168; }
    src += (size_t)b * 256 * S;
    dst = featT + ((size_t)b * S_TOT + soff) * 256;
  } else {
    const int tw = t - 340;
    if (tw < 8)       { src = W_off;  dst = Wcat_t;             S = 256; tb = tw; }
    else if (tw < 12) { src = W_attn; dst = Wcat_t + 256 * 256; S = 128; tb = tw - 8; }
    else if (tw < 20) { src = W_val;  dst = Wval_t;             S = 256; tb = tw - 12; }
    else              { src = W_out;  dst = Wout_t;             S = 256; tb = tw - 20; }
  }
  const int s0 = tb * 32, c0 = blockIdx.y * 32;

  __shared__ float tile[32][33];
  const int tx = threadIdx.x & 31, ty = threadIdx.x >> 5;
#pragma unroll
  for (int j = 0; j < 4; ++j) {
    const int c = c0 + ty + j * 8;
    tile[ty + j * 8][tx] = src[(size_t)c * S + s0 + tx];
  }
  __syncthreads();
#pragma unroll
  for (int j = 0; j < 4; ++j) {
    const int srow = s0 + ty + j * 8;
    dst[(size_t)srow * 256 + c0 + tx] = (f16)tile[tx][ty + j * 8];
  }
}

// ---------------------------------------------------------------------------
// Fused MFMA GEMM (value proj + offset/logit proj in ONE launch).
// blocks [0,680): vals = featT @ Wval_t + b_val            (A f16)
// blocks [680,2216): q @ Wcat_t -> offb (+b_off) / attnb (+b_attn) (A f32 cvt)
// 64x64 tile, 4 waves, whole-K LDS, XOR swizzle slot^(row&7).
// ---------------------------------------------------------------------------
__global__ __launch_bounds__(256) void gemm_fused_kernel(
    const f16* __restrict__ featT, const float* __restrict__ query,
    const f16* __restrict__ Wval_t, const f16* __restrict__ Wcat_t,
    const float* __restrict__ b_val, const float* __restrict__ b_off,
    const float* __restrict__ b_attn,
    f16* __restrict__ vals, f16* __restrict__ offb, f16* __restrict__ attnb) {
  __shared__ f16 As[64][256];
  __shared__ f16 Bs[64][256];
  const int t = blockIdx.x;
  const int tid = threadIdx.x;
  const bool isval = (t < 680);
  size_t r0, c0;
  const f16* Bt;
  if (isval) { r0 = (size_t)(t >> 2) * 64;      c0 = (size_t)(t & 3) * 64;  Bt = Wval_t; }
  else       { const int t2 = t - 680;
               r0 = (size_t)(t2 / 6) * 64;      c0 = (size_t)(t2 % 6) * 64; Bt = Wcat_t; }

  {  // stage tiles: 8 iters x 256 threads
    const f16* gb = Bt + c0 * 256;
    const int row = tid >> 5, slot = tid & 31;
#pragma unroll
    for (int i = 0; i < 8; ++i) {
      const int r = i * 8 + row;
      const int ph = (slot & 24) | ((slot ^ r) & 7);
      if (isval) {
        *(u32x4*)&As[r][ph * 8] =
            *(const u32x4*)(featT + (r0 + r) * 256 + slot * 8);
      } else {
        const float* ga = query + (r0 + r) * 256 + slot * 8;
        const float4 u0 = *(const float4*)ga;
        const float4 u1 = *(const float4*)(ga + 4);
        h8 hv = {(f16)u0.x, (f16)u0.y, (f16)u0.z, (f16)u0.w,
                 (f16)u1.x, (f16)u1.y, (f16)u1.z, (f16)u1.w};
        *(h8*)&As[r][ph * 8] = hv;
      }
      *(u32x4*)&Bs[r][ph * 8] = *(const u32x4*)(gb + (size_t)r * 256 + slot * 8);
    }
  }
  __syncthreads();

  const int wid = tid >> 6, lane = tid & 63;
  const int wr = (wid >> 1) * 32, wc = (wid & 1) * 32;
  const int l15 = lane & 15, l4 = lane >> 4;

  f32x4 acc[2][2] = {};
#pragma unroll
  for (int ks = 0; ks < 8; ++ks) {
    const int slot = ks * 4 + l4;
    h8 a[2], b[2];
#pragma unroll
    for (int m = 0; m < 2; ++m) {
      const int r = wr + m * 16 + l15;
      const int ph = (slot & 24) | ((slot ^ r) & 7);
      a[m] = *(const h8*)&As[r][ph * 8];
    }
#pragma unroll
    for (int n = 0; n < 2; ++n) {
      const int r = wc + n * 16 + l15;
      const int ph = (slot & 24) | ((slot ^ r) & 7);
      b[n] = *(const h8*)&Bs[r][ph * 8];
    }
#pragma unroll
    for (int m = 0; m < 2; ++m)
#pragma unroll
      for (int n = 0; n < 2; ++n)
        acc[m][n] = __builtin_amdgcn_mfma_f32_16x16x32_f16(a[m], b[n], acc[m][n], 0, 0, 0);
  }

  // C/D: col = lane&15, row = (lane>>4)*4 + reg
#pragma unroll
  for (int m = 0; m < 2; ++m)
#pragma unroll
    for (int n = 0; n < 2; ++n)
#pragma unroll
      for (int r = 0; r < 4; ++r) {
        const size_t row = r0 + wr + m * 16 + l4 * 4 + r;
        const size_t col = c0 + wc + n * 16 + l15;
        const float v = acc[m][n][r];
        if (isval) {
          vals[row * 256 + col] = (f16)(v + b_val[col]);
        } else if (c0 < 256) {
          offb[row * 256 + col] = (f16)(v + b_off[col]);
        } else {
          attnb[row * 128 + (col - 256)] = (f16)(v + b_attn[col - 256]);
        }
      }
}

// ---------------------------------------------------------------------------
// Out projection: d_out[M x 256] f32 = samp f16 @ Wout_t^T + b_out.
// ---------------------------------------------------------------------------
__global__ __launch_bounds__(256) void gemm_out_kernel(
    const f16* __restrict__ A, const f16* __restrict__ Bt,
    const float* __restrict__ bias, float* __restrict__ out) {
  __shared__ f16 As[64][256];
  __shared__ f16 Bs[64][256];
  const int tid = threadIdx.x;
  const size_t r0 = (size_t)blockIdx.x * 64;
  const size_t c0 = (size_t)blockIdx.y * 64;

  {
    const f16* ga = A + r0 * 256;
    const f16* gb = Bt + c0 * 256;
    const int row = tid >> 5, slot = tid & 31;
#pragma unroll
    for (int i = 0; i < 8; ++i) {
      const int r = i * 8 + row;
      const int ph = (slot & 24) | ((slot ^ r) & 7);
      *(u32x4*)&As[r][ph * 8] = *(const u32x4*)(ga + (size_t)r * 256 + slot * 8);
      *(u32x4*)&Bs[r][ph * 8] = *(const u32x4*)(gb + (size_t)r * 256 + slot * 8);
    }
  }
  __syncthreads();

  const int wid = tid >> 6, lane = tid & 63;
  const int wr = (wid >> 1) * 32, wc = (wid & 1) * 32;
  const int l15 = lane & 15, l4 = lane >> 4;

  f32x4 acc[2][2] = {};
#pragma unroll
  for (int ks = 0; ks < 8; ++ks) {
    const int slot = ks * 4 + l4;
    h8 a[2], b[2];
#pragma unroll
    for (int m = 0; m < 2; ++m) {
      const int r = wr + m * 16 + l15;
      const int ph = (slot & 24) | ((slot ^ r) & 7);
      a[m] = *(const h8*)&As[r][ph * 8];
    }
#pragma unroll
    for (int n = 0; n < 2; ++n) {
      const int r = wc + n * 16 + l15;
      const int ph = (slot & 24) | ((slot ^ r) & 7);
      b[n] = *(const h8*)&Bs[r][ph * 8];
    }
#pragma unroll
    for (int m = 0; m < 2; ++m)
#pragma unroll
      for (int n = 0; n < 2; ++n)
        acc[m][n] = __builtin_amdgcn_mfma_f32_16x16x32_f16(a[m], b[n], acc[m][n], 0, 0, 0);
  }

#pragma unroll
  for (int m = 0; m < 2; ++m)
#pragma unroll
    for (int n = 0; n < 2; ++n)
#pragma unroll
      for (int r = 0; r < 4; ++r) {
        const size_t row = r0 + wr + m * 16 + l4 * 4 + r;
        const size_t col = c0 + wc + n * 16 + l15;
        out[row * 256 + col] = acc[m][n][r] + bias[col];
      }
}

// ---------------------------------------------------------------------------
// Sampling + softmax + weighted sum, fp16 values.
// Block = 2 queries; per query 8 heads x 16 lanes (grp).
// Phase 1: lane g = point g: softmax weight + bilinear {float4 w, int4 byteoff}
//          into padded LDS.
// Phase 2: lane (c4=g&3, pc=g>>2): channels 8*c4..8*c4+7, corner pc.
//          ALL 16 idx/w read from LDS, then ALL 16 16B gathers issued
//          (vv[16] regs -> 16 outstanding loads: latency hiding), then fma.
//          __shfl_xor(4|8) combines corners; pc==0 stores 16B f16.
// ---------------------------------------------------------------------------
__global__ __launch_bounds__(256) void sample_kernel(
    const f16* __restrict__ vals, const f16* __restrict__ offb,
    const f16* __restrict__ attnb, const float* __restrict__ refp,
    f16* __restrict__ samp) {
  const int tid = threadIdx.x;
  const int g = tid & 15;
  const int grp = tid >> 4;
  const int h = grp & 7;
  const int half = tid >> 7;
  const int bq = blockIdx.x * 2 + half;
  const int b = bq >> 13;

  __shared__ float4 wts[16][17];
  __shared__ int4 idxs[16][17];

  // ---- phase 1 ----
  const float rx = refp[(size_t)bq * 2 + 0];
  const float ry = refp[(size_t)bq * 2 + 1];

  float logit = (float)attnb[(size_t)bq * 128 + h * 16 + g];
  float m = logit;
#pragma unroll
  for (int mask = 1; mask < 16; mask <<= 1)
    m = fmaxf(m, __shfl_xor(m, mask, 16));
  const float e = __expf(logit - m);
  float ssum = e;
#pragma unroll
  for (int mask = 1; mask < 16; mask <<= 1)
    ssum += __shfl_xor(ssum, mask, 16);
  const float aw = e / ssum;

  const h2 ov = *(const h2*)(offb + (size_t)bq * 256 + h * 32 + g * 2);
  const int l = g >> 2;
  const int Wl = 64 >> l;
  const int loff = (l == 0) ? 0 : (l == 1) ? 4096 : (l == 2) ? 5120 : 5376;

  const float px = (rx + (float)ov[0]) * (float)Wl - 0.5f;
  const float py = (ry + (float)ov[1]) * (float)Wl - 0.5f;
  const float fx = floorf(px), fy = floorf(py);
  const float wx = px - fx, wy = py - fy;
  const int x0 = (int)fx, y0 = (int)fy;
  const int x1 = x0 + 1, y1 = y0 + 1;
  const float vx0 = (x0 >= 0 && x0 < Wl) ? 1.f : 0.f;
  const float vx1 = (x1 >= 0 && x1 < Wl) ? 1.f : 0.f;
  const float vy0 = (y0 >= 0 && y0 < Wl) ? 1.f : 0.f;
  const float vy1 = (y1 >= 0 && y1 < Wl) ? 1.f : 0.f;
  const int cx0 = min(max(x0, 0), Wl - 1), cx1 = min(max(x1, 0), Wl - 1);
  const int cy0 = min(max(y0, 0), Wl - 1), cy1 = min(max(y1, 0), Wl - 1);
  const int base = b * S_TOT + loff;
  idxs[grp][g] = make_int4((base + cy0 * Wl + cx0) * 512,
                           (base + cy0 * Wl + cx1) * 512,
                           (base + cy1 * Wl + cx0) * 512,
                           (base + cy1 * Wl + cx1) * 512);
  wts[grp][g] = make_float4(aw * (1.f - wx) * (1.f - wy) * vx0 * vy0,
                            aw * wx * (1.f - wy) * vx1 * vy0,
                            aw * (1.f - wx) * wy * vx0 * vy1,
                            aw * wx * wy * vx1 * vy1);
  __syncthreads();

  // ---- phase 2 ----
  const int c4 = g & 3, pc = g >> 2;
  const char* vb = (const char*)vals + (h * 64 + c4 * 16);

  float wv[16];
  int ids[16];
#pragma unroll
  for (int pt = 0; pt < 16; ++pt) {
    wv[pt] = ((const float*)&wts[grp][pt])[pc];
    ids[pt] = ((const int*)&idxs[grp][pt])[pc];
  }
  h8 vv[16];
#pragma unroll
  for (int pt = 0; pt < 16; ++pt) vv[pt] = *(const h8*)(vb + ids[pt]);

  float a[8] = {};
#pragma unroll
  for (int pt = 0; pt < 16; ++pt) {
#pragma unroll
    for (int k = 0; k < 8; ++k) a[k] = fmaf((float)vv[pt][k], wv[pt], a[k]);
  }
#pragma unroll
  for (int k = 0; k < 8; ++k) {
    a[k] += __shfl_xor(a[k], 4);
    a[k] += __shfl_xor(a[k], 8);
  }
  if (pc == 0) {
    h8 r;
#pragma unroll
    for (int k = 0; k < 8; ++k) r[k] = (f16)a[k];
    *(h8*)(samp + (size_t)bq * 256 + h * 32 + c4 * 8) = r;
  }
}

// ---------------------------------------------------------------------------
extern "C" void kernel_launch(void* const* d_in, const int* in_sizes, int n_in,
                              void* d_out, int out_size, void* d_ws, size_t ws_size,
                              hipStream_t stream) {
  const float* query = (const float*)d_in[0];
  const float* feat[4] = {(const float*)d_in[1], (const float*)d_in[2],
                          (const float*)d_in[3], (const float*)d_in[4]};
  const float* refp  = (const float*)d_in[5];
  const float* W_off = (const float*)d_in[6];
  const float* b_off = (const float*)d_in[7];
  const float* W_attn = (const float*)d_in[8];
  const float* b_attn = (const float*)d_in[9];
  const float* W_val = (const float*)d_in[10];
  const float* b_val = (const float*)d_in[11];
  const float* W_out = (const float*)d_in[12];
  const float* b_out = (const float*)d_in[13];
  float* out = (float*)d_out;

  // ---- workspace layout (f16 units; ~32.6 MB, no aliasing) ----
  f16* ws = (f16*)d_ws;
  f16* featT  = ws;                                  // [10880][256]  5.57MB
  f16* vals   = featT + (size_t)NB * S_TOT * 256;    // [10880][256]  5.57MB
  f16* offb   = vals + (size_t)NB * S_TOT * 256;     // [16384][256]  8.4MB
  f16* samp   = offb + (size_t)NB * QN * 256;        // [16384][256]  8.4MB
  f16* attnb  = samp + (size_t)NB * QN * 256;        // [16384][128]  4.2MB
  f16* Wcat_t = attnb + (size_t)NB * QN * 128;       // [384][256]
  f16* Wval_t = Wcat_t + 384 * 256;                  // [256][256]
  f16* Wout_t = Wval_t + 256 * 256;                  // [256][256]

  // 1. all prep (feat transpose + weight transposes) in one launch
  prep_kernel<<<dim3(368, 8), 256, 0, stream>>>(
      feat[0], feat[1], feat[2], feat[3], W_off, W_attn, W_val, W_out,
      featT, Wcat_t, Wval_t, Wout_t);

  // 2. value proj + offset/logit proj in one launch
  gemm_fused_kernel<<<680 + 1536, 256, 0, stream>>>(
      featT, query, Wval_t, Wcat_t, b_val, b_off, b_attn, vals, offb, attnb);

  // 3. sampling -> samp f16
  sample_kernel<<<(NB * QN) / 2, 256, 0, stream>>>(vals, offb, attnb, refp, samp);

  // 4. out projection: samp @ Wout_t + b_out -> d_out f32
  gemm_out_kernel<<<dim3((NB * QN) / 64, 4), 256, 0, stream>>>(
      samp, Wout_t, b_out, out);
}

// Round 8
// 69.277 us; speedup vs baseline: 1.1689x; 1.1689x over previous
//
#include <hip/hip_runtime.h>
#include <math.h>

#define NB 2
#define QN 8192
#define DIM 256
#define S_TOT 5440   // 4096+1024+256+64

typedef unsigned int uint32;
typedef _Float16 f16;
typedef __attribute__((ext_vector_type(8))) _Float16 h8;   // MFMA A/B frag (4 VGPR)
typedef __attribute__((ext_vector_type(2))) _Float16 h2;
typedef __attribute__((ext_vector_type(4))) float f32x4;   // MFMA C/D frag
typedef __attribute__((ext_vector_type(4))) uint32 u32x4;  // 16B staging

// ---------------------------------------------------------------------------
// Fused prep: ALL transposes/conversions in ONE launch.
// grid.x: [0,340) feat tiles (170 per batch), [340,368) weight tiles.
// src f32 [C=256][S] -> dst f16 [S][256].
// ---------------------------------------------------------------------------
__global__ __launch_bounds__(256) void prep_kernel(
    const float* __restrict__ f0, const float* __restrict__ f1,
    const float* __restrict__ f2, const float* __restrict__ f3,
    const float* __restrict__ W_off, const float* __restrict__ W_attn,
    const float* __restrict__ W_val, const float* __restrict__ W_out,
    f16* __restrict__ featT, f16* __restrict__ Wcat_t,
    f16* __restrict__ Wval_t, f16* __restrict__ Wout_t) {
  const int t = blockIdx.x;
  const float* src;
  f16* dst;
  int S, tb;
  if (t < 340) {
    const int b = (t >= 170) ? 1 : 0;
    const int tt = t - 170 * b;
    int soff;
    if (tt < 128)      { src = f0; S = 4096; soff = 0;    tb = tt; }
    else if (tt < 160) { src = f1; S = 1024; soff = 4096; tb = tt - 128; }
    else if (tt < 168) { src = f2; S = 256;  soff = 5120; tb = tt - 160; }
    else               { src = f3; S = 64;   soff = 5376; tb = tt - 168; }
    src += (size_t)b * 256 * S;
    dst = featT + ((size_t)b * S_TOT + soff) * 256;
  } else {
    const int tw = t - 340;
    if (tw < 8)       { src = W_off;  dst = Wcat_t;             S = 256; tb = tw; }
    else if (tw < 12) { src = W_attn; dst = Wcat_t + 256 * 256; S = 128; tb = tw - 8; }
    else if (tw < 20) { src = W_val;  dst = Wval_t;             S = 256; tb = tw - 12; }
    else              { src = W_out;  dst = Wout_t;             S = 256; tb = tw - 20; }
  }
  const int s0 = tb * 32, c0 = blockIdx.y * 32;

  __shared__ float tile[32][33];
  const int tx = threadIdx.x & 31, ty = threadIdx.x >> 5;
#pragma unroll
  for (int j = 0; j < 4; ++j) {
    const int c = c0 + ty + j * 8;
    tile[ty + j * 8][tx] = src[(size_t)c * S + s0 + tx];
  }
  __syncthreads();
#pragma unroll
  for (int j = 0; j < 4; ++j) {
    const int srow = s0 + ty + j * 8;
    dst[(size_t)srow * 256 + c0 + tx] = (f16)tile[tx][ty + j * 8];
  }
}

// ---------------------------------------------------------------------------
// A-stationary fused MFMA GEMM (value proj + offset/logit proj, ONE launch).
// Block = 64-row stripe; loops over ALL column tiles (A read from HBM once).
// blocks [0,170): vals = featT @ Wval_t + b_val  (NC=4)
// blocks [170,426): q f32 @ Wcat_t -> offb(+b_off) / attnb(+b_attn) (NC=6)
// A-frags cached in regs after first c-tile; B(c+1) reg-prefetched under MFMA.
// ---------------------------------------------------------------------------
__global__ __launch_bounds__(256) void gemm_fused_kernel(
    const f16* __restrict__ featT, const float* __restrict__ query,
    const f16* __restrict__ Wval_t, const f16* __restrict__ Wcat_t,
    const float* __restrict__ b_val, const float* __restrict__ b_off,
    const float* __restrict__ b_attn,
    f16* __restrict__ vals, f16* __restrict__ offb, f16* __restrict__ attnb) {
  __shared__ f16 As[64][256];
  __shared__ f16 Bs[64][256];
  const int t = blockIdx.x;
  const int tid = threadIdx.x;
  const bool isval = (t < 170);
  const size_t r0 = (size_t)(isval ? t : t - 170) * 64;
  const int NC = isval ? 4 : 6;
  const f16* Bt = isval ? Wval_t : Wcat_t;

  const int row = tid >> 5, slot = tid & 31;

  // ---- stage A once (HBM read happens exactly once per row) ----
#pragma unroll
  for (int i = 0; i < 8; ++i) {
    const int r = i * 8 + row;
    const int ph = (slot & 24) | ((slot ^ r) & 7);
    if (isval) {
      *(u32x4*)&As[r][ph * 8] =
          *(const u32x4*)(featT + (r0 + r) * 256 + slot * 8);
    } else {
      const float* ga = query + (r0 + r) * 256 + slot * 8;
      const float4 u0 = *(const float4*)ga;
      const float4 u1 = *(const float4*)(ga + 4);
      h8 hv = {(f16)u0.x, (f16)u0.y, (f16)u0.z, (f16)u0.w,
               (f16)u1.x, (f16)u1.y, (f16)u1.z, (f16)u1.w};
      *(h8*)&As[r][ph * 8] = hv;
    }
  }

  const int wid = tid >> 6, lane = tid & 63;
  const int wr = (wid >> 1) * 32, wc = (wid & 1) * 32;
  const int l15 = lane & 15, l4 = lane >> 4;

  // ---- prefetch B tile 0 into regs ----
  u32x4 bpre[8];
#pragma unroll
  for (int i = 0; i < 8; ++i) {
    bpre[i] = *(const u32x4*)(Bt + (size_t)(i * 8 + row) * 256 + slot * 8);
  }

  h8 areg[8][2];   // A-fragments cached across c-tiles (64 VGPR)

  for (int c = 0; c < NC; ++c) {
    __syncthreads();   // prior iter's Bs reads complete (WAR); A-writes visible
    // commit prefetched B tile to LDS
#pragma unroll
    for (int i = 0; i < 8; ++i) {
      const int r = i * 8 + row;
      const int ph = (slot & 24) | ((slot ^ r) & 7);
      *(u32x4*)&Bs[r][ph * 8] = bpre[i];
    }
    __syncthreads();   // Bs (and on c=0, As) ready

    // issue next B prefetch NOW: flies under the MFMA phase
    if (c + 1 < NC) {
#pragma unroll
      for (int i = 0; i < 8; ++i) {
        bpre[i] = *(const u32x4*)(Bt + (size_t)((c + 1) * 64 + i * 8 + row) * 256 + slot * 8);
      }
    }

    f32x4 acc[2][2] = {};
#pragma unroll
    for (int ks = 0; ks < 8; ++ks) {
      const int slot2 = ks * 4 + l4;
      if (c == 0) {   // wave-uniform branch; fills areg on first tile only
#pragma unroll
        for (int m = 0; m < 2; ++m) {
          const int r = wr + m * 16 + l15;
          const int ph = (slot2 & 24) | ((slot2 ^ r) & 7);
          areg[ks][m] = *(const h8*)&As[r][ph * 8];
        }
      }
      h8 b[2];
#pragma unroll
      for (int n = 0; n < 2; ++n) {
        const int r = wc + n * 16 + l15;
        const int ph = (slot2 & 24) | ((slot2 ^ r) & 7);
        b[n] = *(const h8*)&Bs[r][ph * 8];
      }
#pragma unroll
      for (int m = 0; m < 2; ++m)
#pragma unroll
        for (int n = 0; n < 2; ++n)
          acc[m][n] = __builtin_amdgcn_mfma_f32_16x16x32_f16(areg[ks][m], b[n], acc[m][n], 0, 0, 0);
    }

    // C/D: col = lane&15, row = (lane>>4)*4 + reg
#pragma unroll
    for (int m = 0; m < 2; ++m)
#pragma unroll
      for (int n = 0; n < 2; ++n)
#pragma unroll
        for (int r = 0; r < 4; ++r) {
          const size_t rw = r0 + wr + m * 16 + l4 * 4 + r;
          const int col = c * 64 + wc + n * 16 + l15;
          const float v = acc[m][n][r];
          if (isval) {
            vals[rw * 256 + col] = (f16)(v + b_val[col]);
          } else if (col < 256) {
            offb[rw * 256 + col] = (f16)(v + b_off[col]);
          } else {
            attnb[rw * 128 + (col - 256)] = (f16)(v + b_attn[col - 256]);
          }
        }
  }
}

// ---------------------------------------------------------------------------
// A-stationary out projection: d_out[M x 256] f32 = samp f16 @ Wout_t^T + b_out.
// Block = 64-row stripe, NC=4 c-tiles, same structure as fused GEMM.
// ---------------------------------------------------------------------------
__global__ __launch_bounds__(256) void gemm_out_kernel(
    const f16* __restrict__ A, const f16* __restrict__ Bt,
    const float* __restrict__ bias, float* __restrict__ out) {
  __shared__ f16 As[64][256];
  __shared__ f16 Bs[64][256];
  const int tid = threadIdx.x;
  const size_t r0 = (size_t)blockIdx.x * 64;

  const int row = tid >> 5, slot = tid & 31;
#pragma unroll
  for (int i = 0; i < 8; ++i) {
    const int r = i * 8 + row;
    const int ph = (slot & 24) | ((slot ^ r) & 7);
    *(u32x4*)&As[r][ph * 8] = *(const u32x4*)(A + (r0 + r) * 256 + slot * 8);
  }

  const int wid = tid >> 6, lane = tid & 63;
  const int wr = (wid >> 1) * 32, wc = (wid & 1) * 32;
  const int l15 = lane & 15, l4 = lane >> 4;

  u32x4 bpre[8];
#pragma unroll
  for (int i = 0; i < 8; ++i) {
    bpre[i] = *(const u32x4*)(Bt + (size_t)(i * 8 + row) * 256 + slot * 8);
  }

  h8 areg[8][2];

  for (int c = 0; c < 4; ++c) {
    __syncthreads();
#pragma unroll
    for (int i = 0; i < 8; ++i) {
      const int r = i * 8 + row;
      const int ph = (slot & 24) | ((slot ^ r) & 7);
      *(u32x4*)&Bs[r][ph * 8] = bpre[i];
    }
    __syncthreads();

    if (c + 1 < 4) {
#pragma unroll
      for (int i = 0; i < 8; ++i) {
        bpre[i] = *(const u32x4*)(Bt + (size_t)((c + 1) * 64 + i * 8 + row) * 256 + slot * 8);
      }
    }

    f32x4 acc[2][2] = {};
#pragma unroll
    for (int ks = 0; ks < 8; ++ks) {
      const int slot2 = ks * 4 + l4;
      if (c == 0) {
#pragma unroll
        for (int m = 0; m < 2; ++m) {
          const int r = wr + m * 16 + l15;
          const int ph = (slot2 & 24) | ((slot2 ^ r) & 7);
          areg[ks][m] = *(const h8*)&As[r][ph * 8];
        }
      }
      h8 b[2];
#pragma unroll
      for (int n = 0; n < 2; ++n) {
        const int r = wc + n * 16 + l15;
        const int ph = (slot2 & 24) | ((slot2 ^ r) & 7);
        b[n] = *(const h8*)&Bs[r][ph * 8];
      }
#pragma unroll
      for (int m = 0; m < 2; ++m)
#pragma unroll
        for (int n = 0; n < 2; ++n)
          acc[m][n] = __builtin_amdgcn_mfma_f32_16x16x32_f16(areg[ks][m], b[n], acc[m][n], 0, 0, 0);
    }

#pragma unroll
    for (int m = 0; m < 2; ++m)
#pragma unroll
      for (int n = 0; n < 2; ++n)
#pragma unroll
        for (int r = 0; r < 4; ++r) {
          const size_t rw = r0 + wr + m * 16 + l4 * 4 + r;
          const int col = c * 64 + wc + n * 16 + l15;
          out[rw * 256 + col] = acc[m][n][r] + bias[col];
        }
  }
}

// ---------------------------------------------------------------------------
// Sampling + softmax + weighted sum, fp16 values.  (unchanged from round 7)
// Block = 2 queries; per query 8 heads x 16 lanes (grp).
// Phase 1: lane g = point g: softmax weight + bilinear {float4 w, int4 byteoff}
//          into padded LDS.
// Phase 2: lane (c4=g&3, pc=g>>2): channels 8*c4..8*c4+7, corner pc.
//          All 16 16B gathers issued back-to-back (16 outstanding loads),
//          then fma; __shfl_xor(4|8) combines corners; pc==0 stores 16B f16.
// ---------------------------------------------------------------------------
__global__ __launch_bounds__(256) void sample_kernel(
    const f16* __restrict__ vals, const f16* __restrict__ offb,
    const f16* __restrict__ attnb, const float* __restrict__ refp,
    f16* __restrict__ samp) {
  const int tid = threadIdx.x;
  const int g = tid & 15;
  const int grp = tid >> 4;
  const int h = grp & 7;
  const int half = tid >> 7;
  const int bq = blockIdx.x * 2 + half;
  const int b = bq >> 13;

  __shared__ float4 wts[16][17];
  __shared__ int4 idxs[16][17];

  // ---- phase 1 ----
  const float rx = refp[(size_t)bq * 2 + 0];
  const float ry = refp[(size_t)bq * 2 + 1];

  float logit = (float)attnb[(size_t)bq * 128 + h * 16 + g];
  float m = logit;
#pragma unroll
  for (int mask = 1; mask < 16; mask <<= 1)
    m = fmaxf(m, __shfl_xor(m, mask, 16));
  const float e = __expf(logit - m);
  float ssum = e;
#pragma unroll
  for (int mask = 1; mask < 16; mask <<= 1)
    ssum += __shfl_xor(ssum, mask, 16);
  const float aw = e / ssum;

  const h2 ov = *(const h2*)(offb + (size_t)bq * 256 + h * 32 + g * 2);
  const int l = g >> 2;
  const int Wl = 64 >> l;
  const int loff = (l == 0) ? 0 : (l == 1) ? 4096 : (l == 2) ? 5120 : 5376;

  const float px = (rx + (float)ov[0]) * (float)Wl - 0.5f;
  const float py = (ry + (float)ov[1]) * (float)Wl - 0.5f;
  const float fx = floorf(px), fy = floorf(py);
  const float wx = px - fx, wy = py - fy;
  const int x0 = (int)fx, y0 = (int)fy;
  const int x1 = x0 + 1, y1 = y0 + 1;
  const float vx0 = (x0 >= 0 && x0 < Wl) ? 1.f : 0.f;
  const float vx1 = (x1 >= 0 && x1 < Wl) ? 1.f : 0.f;
  const float vy0 = (y0 >= 0 && y0 < Wl) ? 1.f : 0.f;
  const float vy1 = (y1 >= 0 && y1 < Wl) ? 1.f : 0.f;
  const int cx0 = min(max(x0, 0), Wl - 1), cx1 = min(max(x1, 0), Wl - 1);
  const int cy0 = min(max(y0, 0), Wl - 1), cy1 = min(max(y1, 0), Wl - 1);
  const int base = b * S_TOT + loff;
  idxs[grp][g] = make_int4((base + cy0 * Wl + cx0) * 512,
                           (base + cy0 * Wl + cx1) * 512,
                           (base + cy1 * Wl + cx0) * 512,
                           (base + cy1 * Wl + cx1) * 512);
  wts[grp][g] = make_float4(aw * (1.f - wx) * (1.f - wy) * vx0 * vy0,
                            aw * wx * (1.f - wy) * vx1 * vy0,
                            aw * (1.f - wx) * wy * vx0 * vy1,
                            aw * wx * wy * vx1 * vy1);
  __syncthreads();

  // ---- phase 2 ----
  const int c4 = g & 3, pc = g >> 2;
  const char* vb = (const char*)vals + (h * 64 + c4 * 16);

  float wv[16];
  int ids[16];
#pragma unroll
  for (int pt = 0; pt < 16; ++pt) {
    wv[pt] = ((const float*)&wts[grp][pt])[pc];
    ids[pt] = ((const int*)&idxs[grp][pt])[pc];
  }
  h8 vv[16];
#pragma unroll
  for (int pt = 0; pt < 16; ++pt) vv[pt] = *(const h8*)(vb + ids[pt]);

  float a[8] = {};
#pragma unroll
  for (int pt = 0; pt < 16; ++pt) {
#pragma unroll
    for (int k = 0; k < 8; ++k) a[k] = fmaf((float)vv[pt][k], wv[pt], a[k]);
  }
#pragma unroll
  for (int k = 0; k < 8; ++k) {
    a[k] += __shfl_xor(a[k], 4);
    a[k] += __shfl_xor(a[k], 8);
  }
  if (pc == 0) {
    h8 r;
#pragma unroll
    for (int k = 0; k < 8; ++k) r[k] = (f16)a[k];
    *(h8*)(samp + (size_t)bq * 256 + h * 32 + c4 * 8) = r;
  }
}

// ---------------------------------------------------------------------------
extern "C" void kernel_launch(void* const* d_in, const int* in_sizes, int n_in,
                              void* d_out, int out_size, void* d_ws, size_t ws_size,
                              hipStream_t stream) {
  const float* query = (const float*)d_in[0];
  const float* feat[4] = {(const float*)d_in[1], (const float*)d_in[2],
                          (const float*)d_in[3], (const float*)d_in[4]};
  const float* refp  = (const float*)d_in[5];
  const float* W_off = (const float*)d_in[6];
  const float* b_off = (const float*)d_in[7];
  const float* W_attn = (const float*)d_in[8];
  const float* b_attn = (const float*)d_in[9];
  const float* W_val = (const float*)d_in[10];
  const float* b_val = (const float*)d_in[11];
  const float* W_out = (const float*)d_in[12];
  const float* b_out = (const float*)d_in[13];
  float* out = (float*)d_out;

  // ---- workspace layout (f16 units; ~32.6 MB, no aliasing) ----
  f16* ws = (f16*)d_ws;
  f16* featT  = ws;                                  // [10880][256]  5.57MB
  f16* vals   = featT + (size_t)NB * S_TOT * 256;    // [10880][256]  5.57MB
  f16* offb   = vals + (size_t)NB * S_TOT * 256;     // [16384][256]  8.4MB
  f16* samp   = offb + (size_t)NB * QN * 256;        // [16384][256]  8.4MB
  f16* attnb  = samp + (size_t)NB * QN * 256;        // [16384][128]  4.2MB
  f16* Wcat_t = attnb + (size_t)NB * QN * 128;       // [384][256]
  f16* Wval_t = Wcat_t + 384 * 256;                  // [256][256]
  f16* Wout_t = Wval_t + 256 * 256;                  // [256][256]

  // 1. all prep (feat transpose + weight transposes) in one launch
  prep_kernel<<<dim3(368, 8), 256, 0, stream>>>(
      feat[0], feat[1], feat[2], feat[3], W_off, W_attn, W_val, W_out,
      featT, Wcat_t, Wval_t, Wout_t);

  // 2. value proj + offset/logit proj in one A-stationary launch
  gemm_fused_kernel<<<170 + 256, 256, 0, stream>>>(
      featT, query, Wval_t, Wcat_t, b_val, b_off, b_attn, vals, offb, attnb);

  // 3. sampling -> samp f16
  sample_kernel<<<(NB * QN) / 2, 256, 0, stream>>>(vals, offb, attnb, refp, samp);

  // 4. out projection: samp @ Wout_t + b_out -> d_out f32
  gemm_out_kernel<<<(NB * QN) / 64, 256, 0, stream>>>(samp, Wout_t, b_out, out);
}